// Round 4
// baseline (1071.162 us; speedup 1.0000x reference)
//
#include <hip/hip_runtime.h>

typedef __attribute__((ext_vector_type(8))) short s8v;
typedef __attribute__((ext_vector_type(4))) float f4v;

#if __has_builtin(__builtin_amdgcn_exp2f)
#define EXP2(x) __builtin_amdgcn_exp2f(x)
#else
#define EXP2(x) exp2f(x)
#endif
#if __has_builtin(__builtin_amdgcn_rcpf)
#define RCP(x) __builtin_amdgcn_rcpf(x)
#else
#define RCP(x) (1.0f/(x))
#endif

#define LOG2E 1.4426950408889634f

__device__ __forceinline__ short f2bf(float f) {
    union { float f; unsigned u; } x; x.f = f;
    unsigned r = (x.u + 0x7FFFu + ((x.u >> 16) & 1u)) >> 16;
    return (short)r;
}
__device__ __forceinline__ float bf2f(short s) {
    union { unsigned u; float f; } x; x.u = ((unsigned)(unsigned short)s) << 16;
    return x.f;
}
// LDS-visibility barrier WITHOUT vmcnt drain: prefetch loads / global stores
// stay in flight across the step boundary (m97 lesson: __syncthreads drains vmcnt(0)).
__device__ __forceinline__ void lds_barrier() {
    asm volatile("s_waitcnt lgkmcnt(0)\n\ts_barrier" ::: "memory");
}

// ---------------- weight prep: fp32 -> bf16 B-fragment layout ----------------
// WB1: [dir(2)][tile(32)][chunk(8)][lane(64)][8]  (L1: K = 128 x + 128 h, N=512)
// WB2: [dir(2)][tile(16)][chunk(10)][lane(64)][8] (L2: K = 256 y + 64 h, N=256)
// B-frag: lane l, elem j  <->  B[k = c*32 + (l>>4)*8 + j][n = tile*16 + (l&15)]
// Sigmoid gates (i,f,o) are pre-scaled by -LOG2E so sigm(g)=rcp(1+exp2(g')).
__global__ void prep_weights(const float* __restrict__ k1f, const float* __restrict__ r1f,
                             const float* __restrict__ k1b, const float* __restrict__ r1b,
                             const float* __restrict__ k2f, const float* __restrict__ r2f,
                             const float* __restrict__ k2b, const float* __restrict__ r2b,
                             short* __restrict__ WB1, short* __restrict__ WB2) {
    int idx = blockIdx.x * 256 + threadIdx.x;
    if (idx < 262144) {  // 2*32*8*64*8
        int j = idx & 7, l = (idx >> 3) & 63, c = (idx >> 9) & 7, n = (idx >> 12) & 31, d = (idx >> 17) & 1;
        int coln = n * 16 + (l & 15);
        int k = c * 32 + ((l >> 4) * 8) + j;
        const float* Wk = d ? k1b : k1f;
        const float* Wr = d ? r1b : r1f;
        float v = (c < 4) ? Wk[k * 512 + coln] : Wr[(k - 128) * 512 + coln];
        float sc = ((n >> 3) == 2) ? 1.0f : -LOG2E;  // tile gate: 0=i,1=f,2=cc,3=o
        WB1[idx] = f2bf(v * sc);
    }
    if (idx < 163840) {  // 2*16*10*64*8
        int d = idx / 81920, r0 = idx % 81920;
        int n = r0 / 5120, r1 = r0 % 5120;
        int c = r1 / 512, li = r1 % 512;
        int l = li >> 3, j = li & 7;
        int coln = n * 16 + (l & 15);
        int k = c * 32 + ((l >> 4) * 8) + j;
        const float* Wk = d ? k2b : k2f;
        const float* Wr = d ? r2b : r2f;
        float v = (k < 256) ? Wk[k * 256 + coln] : Wr[(k - 256) * 256 + coln];
        float sc = ((n >> 2) == 2) ? 1.0f : -LOG2E;
        WB2[idx] = f2bf(v * sc);
    }
}

// ---------------- embedding MLP branch (fp32, exact) ----------------
__global__ void embed_kernel(const int* __restrict__ inputA, const float* __restrict__ emb,
                             const float* __restrict__ w1, const float* __restrict__ b1,
                             const float* __restrict__ w2, const float* __restrict__ b2,
                             const float* __restrict__ w3, const float* __restrict__ b3,
                             float* __restrict__ xe) {
    __shared__ float row[600];
    __shared__ float h1[256];
    __shared__ float h2[128];
    int b = blockIdx.x, t = threadIdx.x;
    if (t < 200) {
        int idx = inputA[b * 200 + t];
        row[t * 3 + 0] = emb[idx * 3 + 0];
        row[t * 3 + 1] = emb[idx * 3 + 1];
        row[t * 3 + 2] = emb[idx * 3 + 2];
    }
    __syncthreads();
    float a = b1[t];
    for (int k = 0; k < 600; k++) a += row[k] * w1[k * 256 + t];
    h1[t] = fmaxf(a, 0.f);
    __syncthreads();
    if (t < 128) {
        float a2 = b2[t];
        for (int k = 0; k < 256; k++) a2 += h1[k] * w2[k * 128 + t];
        h2[t] = fmaxf(a2, 0.f);
    }
    __syncthreads();
    if (t < 64) {
        float a3 = b3[t];
        for (int k = 0; k < 128; k++) a3 += h2[k] * w3[k * 64 + t];
        xe[b * 64 + t] = fmaxf(a3, 0.f);
    }
}

// ---------------- GEMM1: xg = x @ Wk + b (both dirs), full-chip parallel ----------------
// xg layout (bf16): [(dir*16+bt)*TC + sl][w(8)][p(2)][lane(64)][8]
//   p=0 packs tiles ti=0,1 (j=r and j=4+r); p=1 packs ti=2,3. tile = w + 8*ti.
// Each block loops `groups` t-groups of 8 slices, weights resident in regs.
__global__ __launch_bounds__(512, 2) void gemm1_kernel(
        const float* __restrict__ x, const short* __restrict__ WB1,
        const float* __restrict__ bbf, const float* __restrict__ bbb,
        short* __restrict__ xg, int t0, int TC, int groups) {
    __shared__ short axf[8 * 4 * 64 * 8];  // [sl][c][lane][8]
    const int tid = threadIdx.x, lane = tid & 63, w = tid >> 6;
    const int btile = blockIdx.x, tgy = blockIdx.y, dir = blockIdx.z;
    const int b0 = btile << 4;
    s8v wf[4][4];
#pragma unroll
    for (int ti = 0; ti < 4; ti++)
#pragma unroll
        for (int c = 0; c < 4; c++)
            wf[ti][c] = *(const s8v*)(WB1 + ((((dir * 32 + (w + 8 * ti)) * 8) + c) * 64 + lane) * 8);
    const float* bb = dir ? bbb : bbf;
    float bias[4];
#pragma unroll
    for (int ti = 0; ti < 4; ti++) {
        const int tile = w + 8 * ti;
        float sc = ((tile >> 3) == 2) ? 1.0f : -LOG2E;
        bias[ti] = sc * bb[tile * 16 + (lane & 15)];
    }
    const size_t sb = dir * 16 + btile;
    const int m = lane & 15, qq = lane >> 4;
    for (int g = 0; g < groups; g++) {
        const int slb = (tgy * groups + g) * 8;
        __syncthreads();
        {   // stage A frags for slice slb + w
            int tglob = t0 + slb + w;
            if (dir) tglob = 511 - tglob;
            const float* xr = x + ((size_t)(b0 + m) * 512 + tglob) * 128 + qq * 8;
#pragma unroll
            for (int c = 0; c < 4; c++) {
                const f4v* p4 = (const f4v*)(xr + c * 32);
                f4v va = p4[0], vb = p4[1];
                s8v v;
#pragma unroll
                for (int j = 0; j < 4; j++) { v[j] = f2bf(va[j]); v[4 + j] = f2bf(vb[j]); }
                *(s8v*)&axf[((w * 4 + c) * 64 + lane) * 8] = v;
            }
        }
        __syncthreads();
#pragma unroll 2
        for (int sl = 0; sl < 8; sl++) {
            s8v a[4];
#pragma unroll
            for (int c = 0; c < 4; c++) a[c] = *(const s8v*)&axf[((sl * 4 + c) * 64 + lane) * 8];
            f4v acc[4];
#pragma unroll
            for (int ti = 0; ti < 4; ti++) { f4v z = {0.f, 0.f, 0.f, 0.f}; acc[ti] = z; }
#pragma unroll
            for (int c = 0; c < 4; c++)
#pragma unroll
                for (int ti = 0; ti < 4; ti++)
                    acc[ti] = __builtin_amdgcn_mfma_f32_16x16x32_bf16(a[c], wf[ti][c], acc[ti], 0, 0, 0);
            short* outp = xg + ((sb * TC + (size_t)(slb + sl)) * 8 + w) * 1024 + lane * 8;
#pragma unroll
            for (int p = 0; p < 2; p++) {
                s8v v;
#pragma unroll
                for (int j = 0; j < 4; j++) {
                    v[j]     = f2bf(acc[2 * p][j]     + bias[2 * p]);
                    v[4 + j] = f2bf(acc[2 * p + 1][j] + bias[2 * p + 1]);
                }
                *(s8v*)(outp + p * 512) = v;
            }
        }
    }
}

// ---------------- GEMM2: yg = y @ Wk2 + b (both dirs) ----------------
// yg layout (bf16): [(dir*16+bt)*TC + sl][w(4)][p(2)][lane(64)][8], tile = w + 4*ti.
__global__ __launch_bounds__(256, 2) void gemm2_kernel(
        const short* __restrict__ yfr, const short* __restrict__ WB2,
        const float* __restrict__ bbf, const float* __restrict__ bbb,
        short* __restrict__ yg, int t0, int TC, int groups) {
    const int tid = threadIdx.x, lane = tid & 63, w = tid >> 6;
    const int btile = blockIdx.x, tgy = blockIdx.y, dir = blockIdx.z;
    s8v wf[4][8];
#pragma unroll
    for (int ti = 0; ti < 4; ti++)
#pragma unroll
        for (int c = 0; c < 8; c++)
            wf[ti][c] = *(const s8v*)(WB2 + ((((dir * 16 + (w + 4 * ti)) * 10) + c) * 64 + lane) * 8);
    const float* bb = dir ? bbb : bbf;
    float bias[4];
#pragma unroll
    for (int ti = 0; ti < 4; ti++) {
        const int tile = w + 4 * ti;
        float sc = ((tile >> 2) == 2) ? 1.0f : -LOG2E;
        bias[ti] = sc * bb[tile * 16 + (lane & 15)];
    }
    const size_t sb = dir * 16 + btile;
    for (int g = 0; g < groups; g++) {
        const int slb = (tgy * groups + g) * 8;
#pragma unroll 2
        for (int sl = 0; sl < 8; sl++) {
            int tglob = t0 + slb + sl;
            if (dir) tglob = 511 - tglob;
            s8v a[8];
#pragma unroll
            for (int c = 0; c < 8; c++)
                a[c] = *(const s8v*)(yfr + (((size_t)(btile * 512 + tglob) * 8) + c) * 512 + lane * 8);
            f4v acc[4];
#pragma unroll
            for (int ti = 0; ti < 4; ti++) { f4v z = {0.f, 0.f, 0.f, 0.f}; acc[ti] = z; }
#pragma unroll
            for (int c = 0; c < 8; c++)
#pragma unroll
                for (int ti = 0; ti < 4; ti++)
                    acc[ti] = __builtin_amdgcn_mfma_f32_16x16x32_bf16(a[c], wf[ti][c], acc[ti], 0, 0, 0);
            short* outp = yg + ((sb * TC + (size_t)(slb + sl)) * 4 + w) * 1024 + lane * 8;
#pragma unroll
            for (int p = 0; p < 2; p++) {
                s8v v;
#pragma unroll
                for (int j = 0; j < 4; j++) {
                    v[j]     = f2bf(acc[2 * p][j]     + bias[2 * p]);
                    v[4 + j] = f2bf(acc[2 * p + 1][j] + bias[2 * p + 1]);
                }
                *(s8v*)(outp + p * 512) = v;
            }
        }
    }
}

// ---------------- LSTM layer 1 recurrence (h@Wr only), 2-step unrolled ----------------
__global__ __launch_bounds__(512, 2) void lstm1_kernel(
        const short* __restrict__ xg, const short* __restrict__ WB1,
        short* __restrict__ yfr, float* __restrict__ c1st, short* __restrict__ h1st,
        int t0, int TC, int first) {
    __shared__ short hA[2048];
    __shared__ short hB[2048];
    const int tid = threadIdx.x, lane = tid & 63, w = tid >> 6;
    const int btile = blockIdx.x & 15, dir = blockIdx.x >> 4;
    const int col = lane & 15, q = lane >> 4, u = (w << 4) + col;
    const int sb = dir * 16 + btile;

    s8v wf[4][4];  // h-part chunks 4..7
#pragma unroll
    for (int ti = 0; ti < 4; ti++)
#pragma unroll
        for (int c = 0; c < 4; c++)
            wf[ti][c] = *(const s8v*)(WB1 + ((((dir * 32 + (w + 8 * ti)) * 8) + 4 + c) * 64 + lane) * 8);

    float cst[4], hl[4];
    if (first) {
#pragma unroll
        for (int r = 0; r < 4; r++) cst[r] = 0.f;
        for (int i = tid; i < 2048; i += 512) hA[i] = 0;
    } else {
        f4v cv = *(const f4v*)(c1st + ((size_t)sb * 8 + w) * 256 + lane * 4);
#pragma unroll
        for (int r = 0; r < 4; r++) cst[r] = cv[r];
        for (int i = tid; i < 2048; i += 512) hA[i] = h1st[sb * 2048 + i];
    }
    __syncthreads();

    const short* xgp = xg + (size_t)sb * TC * 8192 + w * 1024 + lane * 8;
    s8v pe0 = *(const s8v*)(xgp);
    s8v pe1 = *(const s8v*)(xgp + 512);
    s8v po0 = *(const s8v*)(xgp + 8192);
    s8v po1 = *(const s8v*)(xgp + 8192 + 512);

    const int hidx = (w >> 1) * 512 + ((u >> 3) & 3) * 128 + (u & 7);

    for (int s = 0; s < TC; s += 2) {
        // ---- even step s: read hA, write hB ----
        {
            s8v ah[4];
#pragma unroll
            for (int c = 0; c < 4; c++) ah[c] = *(const s8v*)&hA[(c * 64 + lane) * 8];
            if (w >= 4 && s > 0) {  // store h(s-1)
                int tp = t0 + s - 1;
                if (dir) tp = 511 - tp;
                s8v hv = (w == 4) ? ah[0] : (w == 5) ? ah[1] : (w == 6) ? ah[2] : ah[3];
                *(s8v*)(yfr + (((size_t)(btile * 512 + tp) * 8) + dir * 4 + (w - 4)) * 512 + lane * 8) = hv;
            }
            f4v acc[4];
#pragma unroll
            for (int r = 0; r < 4; r++) {
                acc[0][r] = bf2f(pe0[r]);
                acc[1][r] = bf2f(pe0[4 + r]);
                acc[2][r] = bf2f(pe1[r]);
                acc[3][r] = bf2f(pe1[4 + r]);
            }
            {   // prefetch for step s+2 (xg has slack past the end)
                const short* np = xgp + (size_t)(s + 2) * 8192;
                pe0 = *(const s8v*)np;
                pe1 = *(const s8v*)(np + 512);
            }
#pragma unroll
            for (int c = 0; c < 4; c++)
#pragma unroll
                for (int ti = 0; ti < 4; ti++)
                    acc[ti] = __builtin_amdgcn_mfma_f32_16x16x32_bf16(ah[c], wf[ti][c], acc[ti], 0, 0, 0);
#pragma unroll
            for (int r = 0; r < 4; r++) {
                float iv = RCP(1.0f + EXP2(acc[0][r]));
                float fv = RCP(1.0f + EXP2(acc[1][r]));
                float ov = RCP(1.0f + EXP2(acc[3][r]));
                float ccv = fmaxf(acc[2][r], 0.f);
                cst[r] = fv * cst[r] + iv * ccv;
                hl[r] = ov * fmaxf(cst[r], 0.f);
            }
#pragma unroll
            for (int r = 0; r < 4; r++)
                hB[hidx + ((q * 4 + r) << 3)] = f2bf(hl[r]);
            lds_barrier();
        }
        // ---- odd step s+1: read hB, write hA ----
        {
            s8v ah[4];
#pragma unroll
            for (int c = 0; c < 4; c++) ah[c] = *(const s8v*)&hB[(c * 64 + lane) * 8];
            if (w >= 4) {  // store h(s)
                int tp = t0 + s;
                if (dir) tp = 511 - tp;
                s8v hv = (w == 4) ? ah[0] : (w == 5) ? ah[1] : (w == 6) ? ah[2] : ah[3];
                *(s8v*)(yfr + (((size_t)(btile * 512 + tp) * 8) + dir * 4 + (w - 4)) * 512 + lane * 8) = hv;
            }
            f4v acc[4];
#pragma unroll
            for (int r = 0; r < 4; r++) {
                acc[0][r] = bf2f(po0[r]);
                acc[1][r] = bf2f(po0[4 + r]);
                acc[2][r] = bf2f(po1[r]);
                acc[3][r] = bf2f(po1[4 + r]);
            }
            {   // prefetch for step s+3
                const short* np = xgp + (size_t)(s + 3) * 8192;
                po0 = *(const s8v*)np;
                po1 = *(const s8v*)(np + 512);
            }
#pragma unroll
            for (int c = 0; c < 4; c++)
#pragma unroll
                for (int ti = 0; ti < 4; ti++)
                    acc[ti] = __builtin_amdgcn_mfma_f32_16x16x32_bf16(ah[c], wf[ti][c], acc[ti], 0, 0, 0);
#pragma unroll
            for (int r = 0; r < 4; r++) {
                float iv = RCP(1.0f + EXP2(acc[0][r]));
                float fv = RCP(1.0f + EXP2(acc[1][r]));
                float ov = RCP(1.0f + EXP2(acc[3][r]));
                float ccv = fmaxf(acc[2][r], 0.f);
                cst[r] = fv * cst[r] + iv * ccv;
                hl[r] = ov * fmaxf(cst[r], 0.f);
            }
#pragma unroll
            for (int r = 0; r < 4; r++)
                hA[hidx + ((q * 4 + r) << 3)] = f2bf(hl[r]);
            lds_barrier();
        }
    }
    // final h(TC-1) is in hA (last write was an odd step)
    if (w >= 4) {
        int tp = t0 + TC - 1;
        if (dir) tp = 511 - tp;
        s8v hv = *(const s8v*)&hA[((w - 4) * 64 + lane) * 8];
        *(s8v*)(yfr + (((size_t)(btile * 512 + tp) * 8) + dir * 4 + (w - 4)) * 512 + lane * 8) = hv;
    }
    f4v cv;
#pragma unroll
    for (int r = 0; r < 4; r++) cv[r] = cst[r];
    *(f4v*)(c1st + ((size_t)sb * 8 + w) * 256 + lane * 4) = cv;
    for (int i = tid; i < 2048; i += 512) h1st[sb * 2048 + i] = hA[i];
}

// ---------------- LSTM layer 2 recurrence (h@Wr only), 2-step unrolled ----------------
__global__ __launch_bounds__(256, 2) void lstm2_kernel(
        const short* __restrict__ yg, const short* __restrict__ WB2,
        float* __restrict__ c2st, short* __restrict__ h2st, float* __restrict__ h2o,
        int t0, int TC, int first, int last) {
    __shared__ short hA[1024];
    __shared__ short hB[1024];
    const int tid = threadIdx.x, lane = tid & 63, w = tid >> 6;
    const int btile = blockIdx.x & 15, dir = blockIdx.x >> 4;
    const int b0 = btile << 4;
    const int col = lane & 15, q = lane >> 4, u = (w << 4) + col;
    const int sb = dir * 16 + btile;

    s8v wf[4][2];  // h-part chunks 8,9
#pragma unroll
    for (int ti = 0; ti < 4; ti++)
#pragma unroll
        for (int c = 0; c < 2; c++)
            wf[ti][c] = *(const s8v*)(WB2 + ((((dir * 16 + (w + 4 * ti)) * 10) + 8 + c) * 64 + lane) * 8);

    float cst[4], hl[4];
    if (first) {
#pragma unroll
        for (int r = 0; r < 4; r++) cst[r] = 0.f;
        for (int i = tid; i < 1024; i += 256) hA[i] = 0;
    } else {
        f4v cv = *(const f4v*)(c2st + ((size_t)sb * 4 + w) * 256 + lane * 4);
#pragma unroll
        for (int r = 0; r < 4; r++) cst[r] = cv[r];
        for (int i = tid; i < 1024; i += 256) hA[i] = h2st[sb * 1024 + i];
    }
    __syncthreads();

    const short* ygp = yg + (size_t)sb * TC * 4096 + w * 1024 + lane * 8;
    s8v pe0 = *(const s8v*)(ygp);
    s8v pe1 = *(const s8v*)(ygp + 512);
    s8v po0 = *(const s8v*)(ygp + 4096);
    s8v po1 = *(const s8v*)(ygp + 4096 + 512);

    const int hidx = (w >> 1) * 512 + ((u >> 3) & 3) * 128 + (u & 7);

    for (int s = 0; s < TC; s += 2) {
        // ---- even step: read hA, write hB ----
        {
            s8v ah[2];
#pragma unroll
            for (int c = 0; c < 2; c++) ah[c] = *(const s8v*)&hA[(c * 64 + lane) * 8];
            f4v acc[4];
#pragma unroll
            for (int r = 0; r < 4; r++) {
                acc[0][r] = bf2f(pe0[r]);
                acc[1][r] = bf2f(pe0[4 + r]);
                acc[2][r] = bf2f(pe1[r]);
                acc[3][r] = bf2f(pe1[4 + r]);
            }
            {
                const short* np = ygp + (size_t)(s + 2) * 4096;
                pe0 = *(const s8v*)np;
                pe1 = *(const s8v*)(np + 512);
            }
#pragma unroll
            for (int c = 0; c < 2; c++)
#pragma unroll
                for (int ti = 0; ti < 4; ti++)
                    acc[ti] = __builtin_amdgcn_mfma_f32_16x16x32_bf16(ah[c], wf[ti][c], acc[ti], 0, 0, 0);
#pragma unroll
            for (int r = 0; r < 4; r++) {
                float iv = RCP(1.0f + EXP2(acc[0][r]));
                float fv = RCP(1.0f + EXP2(acc[1][r]));
                float ov = RCP(1.0f + EXP2(acc[3][r]));
                float ccv = fmaxf(acc[2][r], 0.f);
                cst[r] = fv * cst[r] + iv * ccv;
                hl[r] = ov * fmaxf(cst[r], 0.f);
            }
#pragma unroll
            for (int r = 0; r < 4; r++)
                hB[hidx + ((q * 4 + r) << 3)] = f2bf(hl[r]);
            lds_barrier();
        }
        // ---- odd step: read hB, write hA ----
        {
            s8v ah[2];
#pragma unroll
            for (int c = 0; c < 2; c++) ah[c] = *(const s8v*)&hB[(c * 64 + lane) * 8];
            f4v acc[4];
#pragma unroll
            for (int r = 0; r < 4; r++) {
                acc[0][r] = bf2f(po0[r]);
                acc[1][r] = bf2f(po0[4 + r]);
                acc[2][r] = bf2f(po1[r]);
                acc[3][r] = bf2f(po1[4 + r]);
            }
            {
                const short* np = ygp + (size_t)(s + 3) * 4096;
                po0 = *(const s8v*)np;
                po1 = *(const s8v*)(np + 512);
            }
#pragma unroll
            for (int c = 0; c < 2; c++)
#pragma unroll
                for (int ti = 0; ti < 4; ti++)
                    acc[ti] = __builtin_amdgcn_mfma_f32_16x16x32_bf16(ah[c], wf[ti][c], acc[ti], 0, 0, 0);
#pragma unroll
            for (int r = 0; r < 4; r++) {
                float iv = RCP(1.0f + EXP2(acc[0][r]));
                float fv = RCP(1.0f + EXP2(acc[1][r]));
                float ov = RCP(1.0f + EXP2(acc[3][r]));
                float ccv = fmaxf(acc[2][r], 0.f);
                cst[r] = fv * cst[r] + iv * ccv;
                hl[r] = ov * fmaxf(cst[r], 0.f);
            }
#pragma unroll
            for (int r = 0; r < 4; r++)
                hA[hidx + ((q * 4 + r) << 3)] = f2bf(hl[r]);
            lds_barrier();
        }
    }
    f4v cv;
#pragma unroll
    for (int r = 0; r < 4; r++) cv[r] = cst[r];
    *(f4v*)(c2st + ((size_t)sb * 4 + w) * 256 + lane * 4) = cv;
    for (int i = tid; i < 1024; i += 256) h2st[sb * 1024 + i] = hA[i];
    if (last) {
#pragma unroll
        for (int r = 0; r < 4; r++)
            h2o[((dir * 256) + b0 + q * 4 + r) * 64 + u] = hl[r];
    }
}

// ---------------- final heads (fp32) ----------------
__global__ void heads_kernel(const float* __restrict__ xe, const float* __restrict__ h2o,
                             const float* __restrict__ wz1, const float* __restrict__ bz1,
                             const float* __restrict__ wz2, const float* __restrict__ bz2,
                             const float* __restrict__ wt1, const float* __restrict__ bt1,
                             const float* __restrict__ wt2, const float* __restrict__ bt2,
                             float* __restrict__ out) {
    int b = threadIdx.x;  // 256 threads, 1 block
    float cz0 = bz1[0], cz1 = bz1[1], ct0 = bt1[0], ct1 = bt1[1];
    for (int k = 0; k < 192; k++) {
        float v = (k < 64) ? xe[b * 64 + k]
                : (k < 128) ? h2o[b * 64 + (k - 64)]
                            : h2o[(256 + b) * 64 + (k - 128)];
        cz0 += v * wz1[k * 2 + 0];
        cz1 += v * wz1[k * 2 + 1];
        ct0 += v * wt1[k * 2 + 0];
        ct1 += v * wt1[k * 2 + 1];
    }
    cz0 = fmaxf(cz0, 0.f); cz1 = fmaxf(cz1, 0.f);
    ct0 = fmaxf(ct0, 0.f); ct1 = fmaxf(ct1, 0.f);
    out[b] = cz0 * wz2[0] + cz1 * wz2[1] + bz2[0];
    out[256 + b] = ct0 * wt2[0] + ct1 * wt2[1] + bt2[0];
}

extern "C" void kernel_launch(void* const* d_in, const int* in_sizes, int n_in,
                              void* d_out, int out_size, void* d_ws, size_t ws_size,
                              hipStream_t stream) {
    const int*   inputA = (const int*)d_in[0];
    const float* inputB = (const float*)d_in[1];
    const float* emb = (const float*)d_in[2];
    const float* w1  = (const float*)d_in[3];
    const float* b1  = (const float*)d_in[4];
    const float* w2  = (const float*)d_in[5];
    const float* b2  = (const float*)d_in[6];
    const float* w3  = (const float*)d_in[7];
    const float* b3  = (const float*)d_in[8];
    const float* k1f = (const float*)d_in[9];
    const float* r1f = (const float*)d_in[10];
    const float* bb1f= (const float*)d_in[11];
    const float* k1b = (const float*)d_in[12];
    const float* r1b = (const float*)d_in[13];
    const float* bb1b= (const float*)d_in[14];
    const float* k2f = (const float*)d_in[15];
    const float* r2f = (const float*)d_in[16];
    const float* bb2f= (const float*)d_in[17];
    const float* k2b = (const float*)d_in[18];
    const float* r2b = (const float*)d_in[19];
    const float* bb2b= (const float*)d_in[20];
    const float* wz1 = (const float*)d_in[21];
    const float* bz1 = (const float*)d_in[22];
    const float* wz2 = (const float*)d_in[23];
    const float* bz2 = (const float*)d_in[24];
    const float* wt1 = (const float*)d_in[25];
    const float* bt1 = (const float*)d_in[26];
    const float* wt2 = (const float*)d_in[27];
    const float* bt2 = (const float*)d_in[28];

    char* ws = (char*)d_ws;
    short* WB1  = (short*)(ws);                  // 512 KB
    short* WB2  = (short*)(ws + 524288);         // 320 KB
    float* xe   = (float*)(ws + 851968);         // 64 KB
    float* h2o  = (float*)(ws + 917504);         // 128 KB
    float* c1st = (float*)(ws + 1048576);        // 256 KB
    short* h1st = (short*)(ws + 1310720);        // 128 KB
    float* c2st = (float*)(ws + 1441792);        // 128 KB
    short* h2st = (short*)(ws + 1572864);        // 64 KB
    short* yfr  = (short*)(ws + 2097152);        // 67.1 MB
    short* xg   = (short*)(ws + 69206016);       // TC*512 KB + 64 KB slack (shared xg/yg)
    float* out  = (float*)d_out;

    // pick time-chunk length from available workspace (64 KB slack for prefetch over-read)
    const size_t fixed = 69206016;
    int TC = 32;
    const int cands[5] = {512, 256, 128, 64, 32};
    for (int i = 0; i < 5; i++) {
        if (fixed + (size_t)cands[i] * 524288 + 65536 <= ws_size) { TC = cands[i]; break; }
    }
    const int NC = 512 / TC;
    const int gy = (TC >= 64) ? (TC / 64) : 1;
    const int groups = TC / (8 * gy);

    prep_weights<<<1024, 256, 0, stream>>>(k1f, r1f, k1b, r1b, k2f, r2f, k2b, r2b, WB1, WB2);
    embed_kernel<<<256, 256, 0, stream>>>(inputA, emb, w1, b1, w2, b2, w3, b3, xe);
    for (int c = 0; c < NC; c++) {
        int t0 = c * TC;
        gemm1_kernel<<<dim3(16, gy, 2), 512, 0, stream>>>(inputB, WB1, bb1f, bb1b, xg, t0, TC, groups);
        lstm1_kernel<<<32, 512, 0, stream>>>(xg, WB1, yfr, c1st, h1st, t0, TC, c == 0);
    }
    for (int c = 0; c < NC; c++) {
        int t0 = c * TC;
        gemm2_kernel<<<dim3(16, gy, 2), 256, 0, stream>>>(yfr, WB2, bb2f, bb2b, xg, t0, TC, groups);
        lstm2_kernel<<<32, 256, 0, stream>>>(xg, WB2, c2st, h2st, h2o, t0, TC, c == 0, c == NC - 1);
    }
    heads_kernel<<<1, 256, 0, stream>>>(xe, h2o, wz1, bz1, wz2, bz2, wt1, bt1, wt2, bt2, out);
}

// Round 5
// 909.236 us; speedup vs baseline: 1.1781x; 1.1781x over previous
//
#include <hip/hip_runtime.h>

typedef __attribute__((ext_vector_type(8))) short s8v;
typedef __attribute__((ext_vector_type(4))) short s4v;
typedef __attribute__((ext_vector_type(4))) float f4v;

#if __has_builtin(__builtin_amdgcn_exp2f)
#define EXP2(x) __builtin_amdgcn_exp2f(x)
#else
#define EXP2(x) exp2f(x)
#endif
#if __has_builtin(__builtin_amdgcn_rcpf)
#define RCP(x) __builtin_amdgcn_rcpf(x)
#else
#define RCP(x) (1.0f/(x))
#endif

#define LOG2E 1.4426950408889634f

__device__ __forceinline__ short f2bf(float f) {
    union { float f; unsigned u; } x; x.f = f;
    unsigned r = (x.u + 0x7FFFu + ((x.u >> 16) & 1u)) >> 16;
    return (short)r;
}
__device__ __forceinline__ float bf2f(short s) {
    union { unsigned u; float f; } x; x.u = ((unsigned)(unsigned short)s) << 16;
    return x.f;
}
// LDS-visibility barrier WITHOUT vmcnt drain (keeps prefetch/stores in flight).
__device__ __forceinline__ void lds_barrier() {
    asm volatile("s_waitcnt lgkmcnt(0)\n\ts_barrier" ::: "memory");
}

// ---------------- weight prep: fp32 -> bf16 B-fragment layout ----------------
// WB1: [dir(2)][tile(32)][chunk(8)][lane(64)][8]  (L1: K = 128 x + 128 h, N=512)
// WB2: [dir(2)][tile(16)][chunk(10)][lane(64)][8] (L2: K = 256 y + 64 h, N=256)
// B-frag: lane l, elem j  <->  B[k = c*32 + (l>>4)*8 + j][n = tile*16 + (l&15)]
// Sigmoid gates (i,f,o) pre-scaled by -LOG2E so sigm(g)=rcp(1+exp2(g')).
__global__ void prep_weights(const float* __restrict__ k1f, const float* __restrict__ r1f,
                             const float* __restrict__ k1b, const float* __restrict__ r1b,
                             const float* __restrict__ k2f, const float* __restrict__ r2f,
                             const float* __restrict__ k2b, const float* __restrict__ r2b,
                             short* __restrict__ WB1, short* __restrict__ WB2) {
    int idx = blockIdx.x * 256 + threadIdx.x;
    if (idx < 262144) {  // 2*32*8*64*8
        int j = idx & 7, l = (idx >> 3) & 63, c = (idx >> 9) & 7, n = (idx >> 12) & 31, d = (idx >> 17) & 1;
        int coln = n * 16 + (l & 15);
        int k = c * 32 + ((l >> 4) * 8) + j;
        const float* Wk = d ? k1b : k1f;
        const float* Wr = d ? r1b : r1f;
        float v = (c < 4) ? Wk[k * 512 + coln] : Wr[(k - 128) * 512 + coln];
        float sc = ((n >> 3) == 2) ? 1.0f : -LOG2E;  // gate: 0=i,1=f,2=cc,3=o
        WB1[idx] = f2bf(v * sc);
    }
    if (idx < 163840) {  // 2*16*10*64*8
        int d = idx / 81920, r0 = idx % 81920;
        int n = r0 / 5120, r1 = r0 % 5120;
        int c = r1 / 512, li = r1 % 512;
        int l = li >> 3, j = li & 7;
        int coln = n * 16 + (l & 15);
        int k = c * 32 + ((l >> 4) * 8) + j;
        const float* Wk = d ? k2b : k2f;
        const float* Wr = d ? r2b : r2f;
        float v = (k < 256) ? Wk[k * 256 + coln] : Wr[(k - 256) * 256 + coln];
        float sc = ((n >> 2) == 2) ? 1.0f : -LOG2E;
        WB2[idx] = f2bf(v * sc);
    }
}

// ---------------- embedding MLP branch (fp32, exact) ----------------
__global__ void embed_kernel(const int* __restrict__ inputA, const float* __restrict__ emb,
                             const float* __restrict__ w1, const float* __restrict__ b1,
                             const float* __restrict__ w2, const float* __restrict__ b2,
                             const float* __restrict__ w3, const float* __restrict__ b3,
                             float* __restrict__ xe) {
    __shared__ float row[600];
    __shared__ float h1[256];
    __shared__ float h2[128];
    int b = blockIdx.x, t = threadIdx.x;
    if (t < 200) {
        int idx = inputA[b * 200 + t];
        row[t * 3 + 0] = emb[idx * 3 + 0];
        row[t * 3 + 1] = emb[idx * 3 + 1];
        row[t * 3 + 2] = emb[idx * 3 + 2];
    }
    __syncthreads();
    float a = b1[t];
    for (int k = 0; k < 600; k++) a += row[k] * w1[k * 256 + t];
    h1[t] = fmaxf(a, 0.f);
    __syncthreads();
    if (t < 128) {
        float a2 = b2[t];
        for (int k = 0; k < 256; k++) a2 += h1[k] * w2[k * 128 + t];
        h2[t] = fmaxf(a2, 0.f);
    }
    __syncthreads();
    if (t < 64) {
        float a3 = b3[t];
        for (int k = 0; k < 128; k++) a3 += h2[k] * w3[k * 64 + t];
        xe[b * 64 + t] = fmaxf(a3, 0.f);
    }
}

// ---------------- GEMM1: xg = x @ Wk + b (both dirs), full-chip parallel ----------------
// xg layout (bf16): [(dir*16+bt)*TC + sl][w(8)][p(2)][lane(64)][8]
//   p=0 packs tiles ti=0,1 (j=r and j=4+r); p=1 packs ti=2,3. tile = w + 8*ti.
// Staging: coalesced 512B row-segment loads + XOR-swizzled LDS scatter
//   (writes <=2-way conflict, reads are a lane permutation: conflict-free).
__global__ __launch_bounds__(512, 2) void gemm1_kernel(
        const float* __restrict__ x, const short* __restrict__ WB1,
        const float* __restrict__ bbf, const float* __restrict__ bbb,
        short* __restrict__ xg, int t0, int TC) {
    __shared__ short axf[8 * 4 * 64 * 8];  // [sl][c][slot(64)][8], slot swizzled
    const int tid = threadIdx.x, lane = tid & 63, w = tid >> 6;
    const int btile = blockIdx.x, tg = blockIdx.y, dir = blockIdx.z;
    const int b0 = btile << 4;
    {   // stage A frags for slice sl = w (coalesced)
        int tglob = t0 + tg * 8 + w;
        if (dir) tglob = 511 - tglob;
        const int half = lane >> 5;
        const int f0 = (lane & 31) * 4;            // k-offset 0..124
        const int c = f0 >> 5, qq = (f0 >> 3) & 3, j0 = f0 & 7;  // j0 in {0,4}
#pragma unroll
        for (int rr = 0; rr < 8; rr++) {
            const int m = rr * 2 + half;
            const float* xp = x + ((size_t)(b0 + m) * 512 + tglob) * 128 + f0;
            f4v v4 = *(const f4v*)xp;
            const int slot = (qq << 4) | ((m ^ qq ^ (c << 1)) & 15);
            s4v pk;
#pragma unroll
            for (int j = 0; j < 4; j++) pk[j] = f2bf(v4[j]);
            *(s4v*)&axf[(((w * 4 + c) * 64 + slot) * 8) + j0] = pk;
        }
    }
    s8v wf[4][4];
#pragma unroll
    for (int ti = 0; ti < 4; ti++)
#pragma unroll
        for (int c = 0; c < 4; c++)
            wf[ti][c] = *(const s8v*)(WB1 + ((((dir * 32 + (w + 8 * ti)) * 8) + c) * 64 + lane) * 8);
    const float* bb = dir ? bbb : bbf;
    float bias[4];
#pragma unroll
    for (int ti = 0; ti < 4; ti++) {
        const int tile = w + 8 * ti;
        float sc = ((tile >> 3) == 2) ? 1.0f : -LOG2E;
        bias[ti] = sc * bb[tile * 16 + (lane & 15)];
    }
    __syncthreads();
    const size_t sb = dir * 16 + btile;
#pragma unroll 2
    for (int sl = 0; sl < 8; sl++) {
        s8v a[4];
#pragma unroll
        for (int c = 0; c < 4; c++) {
            const int slot = lane ^ (lane >> 4) ^ (c << 1);
            a[c] = *(const s8v*)&axf[((sl * 4 + c) * 64 + slot) * 8];
        }
        f4v acc[4];
#pragma unroll
        for (int ti = 0; ti < 4; ti++) { f4v z = {0.f, 0.f, 0.f, 0.f}; acc[ti] = z; }
#pragma unroll
        for (int c = 0; c < 4; c++)
#pragma unroll
            for (int ti = 0; ti < 4; ti++)
                acc[ti] = __builtin_amdgcn_mfma_f32_16x16x32_bf16(a[c], wf[ti][c], acc[ti], 0, 0, 0);
        short* outp = xg + ((sb * TC + (size_t)(tg * 8 + sl)) * 8 + w) * 1024 + lane * 8;
#pragma unroll
        for (int p = 0; p < 2; p++) {
            s8v v;
#pragma unroll
            for (int j = 0; j < 4; j++) {
                v[j]     = f2bf(acc[2 * p][j]     + bias[2 * p]);
                v[4 + j] = f2bf(acc[2 * p + 1][j] + bias[2 * p + 1]);
            }
            *(s8v*)(outp + p * 512) = v;
        }
    }
}

// ---------------- GEMM2: yg = y @ Wk2 + b (both dirs) ----------------
// yg layout (bf16): [(dir*16+bt)*TC + sl][w(4)][p(2)][lane(64)][8], tile = w + 4*ti.
__global__ __launch_bounds__(256, 2) void gemm2_kernel(
        const short* __restrict__ yfr, const short* __restrict__ WB2,
        const float* __restrict__ bbf, const float* __restrict__ bbb,
        short* __restrict__ yg, int t0, int TC) {
    const int tid = threadIdx.x, lane = tid & 63, w = tid >> 6;
    const int btile = blockIdx.x, tg = blockIdx.y, dir = blockIdx.z;
    s8v wf[4][8];
#pragma unroll
    for (int ti = 0; ti < 4; ti++)
#pragma unroll
        for (int c = 0; c < 8; c++)
            wf[ti][c] = *(const s8v*)(WB2 + ((((dir * 16 + (w + 4 * ti)) * 10) + c) * 64 + lane) * 8);
    const float* bb = dir ? bbb : bbf;
    float bias[4];
#pragma unroll
    for (int ti = 0; ti < 4; ti++) {
        const int tile = w + 4 * ti;
        float sc = ((tile >> 2) == 2) ? 1.0f : -LOG2E;
        bias[ti] = sc * bb[tile * 16 + (lane & 15)];
    }
    const size_t sb = dir * 16 + btile;
#pragma unroll 2
    for (int sl = 0; sl < 8; sl++) {
        int tglob = t0 + tg * 8 + sl;
        if (dir) tglob = 511 - tglob;
        s8v a[8];
#pragma unroll
        for (int c = 0; c < 8; c++)
            a[c] = *(const s8v*)(yfr + (((size_t)(btile * 512 + tglob) * 8) + c) * 512 + lane * 8);
        f4v acc[4];
#pragma unroll
        for (int ti = 0; ti < 4; ti++) { f4v z = {0.f, 0.f, 0.f, 0.f}; acc[ti] = z; }
#pragma unroll
        for (int c = 0; c < 8; c++)
#pragma unroll
            for (int ti = 0; ti < 4; ti++)
                acc[ti] = __builtin_amdgcn_mfma_f32_16x16x32_bf16(a[c], wf[ti][c], acc[ti], 0, 0, 0);
        short* outp = yg + ((sb * TC + (size_t)(tg * 8 + sl)) * 4 + w) * 1024 + lane * 8;
#pragma unroll
        for (int p = 0; p < 2; p++) {
            s8v v;
#pragma unroll
            for (int j = 0; j < 4; j++) {
                v[j]     = f2bf(acc[2 * p][j]     + bias[2 * p]);
                v[4 + j] = f2bf(acc[2 * p + 1][j] + bias[2 * p + 1]);
            }
            *(s8v*)(outp + p * 512) = v;
        }
    }
}

// ---------------- LSTM layer 1 recurrence (h@Wr only), 2-step unrolled ----------------
__global__ __launch_bounds__(512, 2) void lstm1_kernel(
        const short* __restrict__ xg, const short* __restrict__ WB1,
        short* __restrict__ yfr, float* __restrict__ c1st, short* __restrict__ h1st,
        int t0, int TC, int first) {
    __shared__ short hA[2048];
    __shared__ short hB[2048];
    const int tid = threadIdx.x, lane = tid & 63, w = tid >> 6;
    const int btile = blockIdx.x & 15, dir = blockIdx.x >> 4;
    const int col = lane & 15, q = lane >> 4, u = (w << 4) + col;
    const int sb = dir * 16 + btile;

    s8v wf[4][4];  // h-part chunks 4..7
#pragma unroll
    for (int ti = 0; ti < 4; ti++)
#pragma unroll
        for (int c = 0; c < 4; c++)
            wf[ti][c] = *(const s8v*)(WB1 + ((((dir * 32 + (w + 8 * ti)) * 8) + 4 + c) * 64 + lane) * 8);

    float cst[4], hl[4];
    if (first) {
#pragma unroll
        for (int r = 0; r < 4; r++) cst[r] = 0.f;
        for (int i = tid; i < 2048; i += 512) hA[i] = 0;
    } else {
        f4v cv = *(const f4v*)(c1st + ((size_t)sb * 8 + w) * 256 + lane * 4);
#pragma unroll
        for (int r = 0; r < 4; r++) cst[r] = cv[r];
        for (int i = tid; i < 2048; i += 512) hA[i] = h1st[sb * 2048 + i];
    }
    __syncthreads();

    const short* xgp = xg + (size_t)sb * TC * 8192 + w * 1024 + lane * 8;
    s8v pe0 = *(const s8v*)(xgp);
    s8v pe1 = *(const s8v*)(xgp + 512);
    s8v po0 = *(const s8v*)(xgp + 8192);
    s8v po1 = *(const s8v*)(xgp + 8192 + 512);

    const int hidx = (w >> 1) * 512 + ((u >> 3) & 3) * 128 + (u & 7);

    for (int s = 0; s < TC; s += 2) {
        // ---- even step s: read hA, write hB ----
        {
            s8v ah[4];
#pragma unroll
            for (int c = 0; c < 4; c++) ah[c] = *(const s8v*)&hA[(c * 64 + lane) * 8];
            if (w >= 4 && s > 0) {  // store h(s-1)
                int tp = t0 + s - 1;
                if (dir) tp = 511 - tp;
                s8v hv = (w == 4) ? ah[0] : (w == 5) ? ah[1] : (w == 6) ? ah[2] : ah[3];
                *(s8v*)(yfr + (((size_t)(btile * 512 + tp) * 8) + dir * 4 + (w - 4)) * 512 + lane * 8) = hv;
            }
            f4v acc[4];
#pragma unroll
            for (int r = 0; r < 4; r++) {
                acc[0][r] = bf2f(pe0[r]);
                acc[1][r] = bf2f(pe0[4 + r]);
                acc[2][r] = bf2f(pe1[r]);
                acc[3][r] = bf2f(pe1[4 + r]);
            }
            {   // prefetch for step s+2 (xg has slack past the end)
                const short* np = xgp + (size_t)(s + 2) * 8192;
                pe0 = *(const s8v*)np;
                pe1 = *(const s8v*)(np + 512);
            }
#pragma unroll
            for (int c = 0; c < 4; c++)
#pragma unroll
                for (int ti = 0; ti < 4; ti++)
                    acc[ti] = __builtin_amdgcn_mfma_f32_16x16x32_bf16(ah[c], wf[ti][c], acc[ti], 0, 0, 0);
#pragma unroll
            for (int r = 0; r < 4; r++) {
                float iv = RCP(1.0f + EXP2(acc[0][r]));
                float fv = RCP(1.0f + EXP2(acc[1][r]));
                float ov = RCP(1.0f + EXP2(acc[3][r]));
                float ccv = fmaxf(acc[2][r], 0.f);
                cst[r] = fv * cst[r] + iv * ccv;
                hl[r] = ov * fmaxf(cst[r], 0.f);
            }
#pragma unroll
            for (int r = 0; r < 4; r++)
                hB[hidx + ((q * 4 + r) << 3)] = f2bf(hl[r]);
            lds_barrier();
        }
        // ---- odd step s+1: read hB, write hA ----
        {
            s8v ah[4];
#pragma unroll
            for (int c = 0; c < 4; c++) ah[c] = *(const s8v*)&hB[(c * 64 + lane) * 8];
            if (w >= 4) {  // store h(s)
                int tp = t0 + s;
                if (dir) tp = 511 - tp;
                s8v hv = (w == 4) ? ah[0] : (w == 5) ? ah[1] : (w == 6) ? ah[2] : ah[3];
                *(s8v*)(yfr + (((size_t)(btile * 512 + tp) * 8) + dir * 4 + (w - 4)) * 512 + lane * 8) = hv;
            }
            f4v acc[4];
#pragma unroll
            for (int r = 0; r < 4; r++) {
                acc[0][r] = bf2f(po0[r]);
                acc[1][r] = bf2f(po0[4 + r]);
                acc[2][r] = bf2f(po1[r]);
                acc[3][r] = bf2f(po1[4 + r]);
            }
            {   // prefetch for step s+3
                const short* np = xgp + (size_t)(s + 3) * 8192;
                po0 = *(const s8v*)np;
                po1 = *(const s8v*)(np + 512);
            }
#pragma unroll
            for (int c = 0; c < 4; c++)
#pragma unroll
                for (int ti = 0; ti < 4; ti++)
                    acc[ti] = __builtin_amdgcn_mfma_f32_16x16x32_bf16(ah[c], wf[ti][c], acc[ti], 0, 0, 0);
#pragma unroll
            for (int r = 0; r < 4; r++) {
                float iv = RCP(1.0f + EXP2(acc[0][r]));
                float fv = RCP(1.0f + EXP2(acc[1][r]));
                float ov = RCP(1.0f + EXP2(acc[3][r]));
                float ccv = fmaxf(acc[2][r], 0.f);
                cst[r] = fv * cst[r] + iv * ccv;
                hl[r] = ov * fmaxf(cst[r], 0.f);
            }
#pragma unroll
            for (int r = 0; r < 4; r++)
                hA[hidx + ((q * 4 + r) << 3)] = f2bf(hl[r]);
            lds_barrier();
        }
    }
    // final h(TC-1) is in hA (last write was an odd step)
    if (w >= 4) {
        int tp = t0 + TC - 1;
        if (dir) tp = 511 - tp;
        s8v hv = *(const s8v*)&hA[((w - 4) * 64 + lane) * 8];
        *(s8v*)(yfr + (((size_t)(btile * 512 + tp) * 8) + dir * 4 + (w - 4)) * 512 + lane * 8) = hv;
    }
    f4v cv;
#pragma unroll
    for (int r = 0; r < 4; r++) cv[r] = cst[r];
    *(f4v*)(c1st + ((size_t)sb * 8 + w) * 256 + lane * 4) = cv;
    for (int i = tid; i < 2048; i += 512) h1st[sb * 2048 + i] = hA[i];
}

// ---------------- LSTM layer 2 recurrence (h@Wr only), 2-step unrolled ----------------
__global__ __launch_bounds__(256, 2) void lstm2_kernel(
        const short* __restrict__ yg, const short* __restrict__ WB2,
        float* __restrict__ c2st, short* __restrict__ h2st, float* __restrict__ h2o,
        int t0, int TC, int first, int last) {
    __shared__ short hA[1024];
    __shared__ short hB[1024];
    const int tid = threadIdx.x, lane = tid & 63, w = tid >> 6;
    const int btile = blockIdx.x & 15, dir = blockIdx.x >> 4;
    const int b0 = btile << 4;
    const int col = lane & 15, q = lane >> 4, u = (w << 4) + col;
    const int sb = dir * 16 + btile;

    s8v wf[4][2];  // h-part chunks 8,9
#pragma unroll
    for (int ti = 0; ti < 4; ti++)
#pragma unroll
        for (int c = 0; c < 2; c++)
            wf[ti][c] = *(const s8v*)(WB2 + ((((dir * 16 + (w + 4 * ti)) * 10) + 8 + c) * 64 + lane) * 8);

    float cst[4], hl[4];
    if (first) {
#pragma unroll
        for (int r = 0; r < 4; r++) cst[r] = 0.f;
        for (int i = tid; i < 1024; i += 256) hA[i] = 0;
    } else {
        f4v cv = *(const f4v*)(c2st + ((size_t)sb * 4 + w) * 256 + lane * 4);
#pragma unroll
        for (int r = 0; r < 4; r++) cst[r] = cv[r];
        for (int i = tid; i < 1024; i += 256) hA[i] = h2st[sb * 1024 + i];
    }
    __syncthreads();

    const short* ygp = yg + (size_t)sb * TC * 4096 + w * 1024 + lane * 8;
    s8v pe0 = *(const s8v*)(ygp);
    s8v pe1 = *(const s8v*)(ygp + 512);
    s8v po0 = *(const s8v*)(ygp + 4096);
    s8v po1 = *(const s8v*)(ygp + 4096 + 512);

    const int hidx = (w >> 1) * 512 + ((u >> 3) & 3) * 128 + (u & 7);

    for (int s = 0; s < TC; s += 2) {
        // ---- even step: read hA, write hB ----
        {
            s8v ah[2];
#pragma unroll
            for (int c = 0; c < 2; c++) ah[c] = *(const s8v*)&hA[(c * 64 + lane) * 8];
            f4v acc[4];
#pragma unroll
            for (int r = 0; r < 4; r++) {
                acc[0][r] = bf2f(pe0[r]);
                acc[1][r] = bf2f(pe0[4 + r]);
                acc[2][r] = bf2f(pe1[r]);
                acc[3][r] = bf2f(pe1[4 + r]);
            }
            {
                const short* np = ygp + (size_t)(s + 2) * 4096;
                pe0 = *(const s8v*)np;
                pe1 = *(const s8v*)(np + 512);
            }
#pragma unroll
            for (int c = 0; c < 2; c++)
#pragma unroll
                for (int ti = 0; ti < 4; ti++)
                    acc[ti] = __builtin_amdgcn_mfma_f32_16x16x32_bf16(ah[c], wf[ti][c], acc[ti], 0, 0, 0);
#pragma unroll
            for (int r = 0; r < 4; r++) {
                float iv = RCP(1.0f + EXP2(acc[0][r]));
                float fv = RCP(1.0f + EXP2(acc[1][r]));
                float ov = RCP(1.0f + EXP2(acc[3][r]));
                float ccv = fmaxf(acc[2][r], 0.f);
                cst[r] = fv * cst[r] + iv * ccv;
                hl[r] = ov * fmaxf(cst[r], 0.f);
            }
#pragma unroll
            for (int r = 0; r < 4; r++)
                hB[hidx + ((q * 4 + r) << 3)] = f2bf(hl[r]);
            lds_barrier();
        }
        // ---- odd step: read hB, write hA ----
        {
            s8v ah[2];
#pragma unroll
            for (int c = 0; c < 2; c++) ah[c] = *(const s8v*)&hB[(c * 64 + lane) * 8];
            f4v acc[4];
#pragma unroll
            for (int r = 0; r < 4; r++) {
                acc[0][r] = bf2f(po0[r]);
                acc[1][r] = bf2f(po0[4 + r]);
                acc[2][r] = bf2f(po1[r]);
                acc[3][r] = bf2f(po1[4 + r]);
            }
            {
                const short* np = ygp + (size_t)(s + 3) * 4096;
                po0 = *(const s8v*)np;
                po1 = *(const s8v*)(np + 512);
            }
#pragma unroll
            for (int c = 0; c < 2; c++)
#pragma unroll
                for (int ti = 0; ti < 4; ti++)
                    acc[ti] = __builtin_amdgcn_mfma_f32_16x16x32_bf16(ah[c], wf[ti][c], acc[ti], 0, 0, 0);
#pragma unroll
            for (int r = 0; r < 4; r++) {
                float iv = RCP(1.0f + EXP2(acc[0][r]));
                float fv = RCP(1.0f + EXP2(acc[1][r]));
                float ov = RCP(1.0f + EXP2(acc[3][r]));
                float ccv = fmaxf(acc[2][r], 0.f);
                cst[r] = fv * cst[r] + iv * ccv;
                hl[r] = ov * fmaxf(cst[r], 0.f);
            }
#pragma unroll
            for (int r = 0; r < 4; r++)
                hA[hidx + ((q * 4 + r) << 3)] = f2bf(hl[r]);
            lds_barrier();
        }
    }
    f4v cv;
#pragma unroll
    for (int r = 0; r < 4; r++) cv[r] = cst[r];
    *(f4v*)(c2st + ((size_t)sb * 4 + w) * 256 + lane * 4) = cv;
    for (int i = tid; i < 1024; i += 256) h2st[sb * 1024 + i] = hA[i];
    if (last) {
#pragma unroll
        for (int r = 0; r < 4; r++)
            h2o[((dir * 256) + b0 + q * 4 + r) * 64 + u] = hl[r];
    }
}

// ---------------- final heads (fp32) ----------------
__global__ void heads_kernel(const float* __restrict__ xe, const float* __restrict__ h2o,
                             const float* __restrict__ wz1, const float* __restrict__ bz1,
                             const float* __restrict__ wz2, const float* __restrict__ bz2,
                             const float* __restrict__ wt1, const float* __restrict__ bt1,
                             const float* __restrict__ wt2, const float* __restrict__ bt2,
                             float* __restrict__ out) {
    int b = threadIdx.x;  // 256 threads, 1 block
    float cz0 = bz1[0], cz1 = bz1[1], ct0 = bt1[0], ct1 = bt1[1];
    for (int k = 0; k < 192; k++) {
        float v = (k < 64) ? xe[b * 64 + k]
                : (k < 128) ? h2o[b * 64 + (k - 64)]
                            : h2o[(256 + b) * 64 + (k - 128)];
        cz0 += v * wz1[k * 2 + 0];
        cz1 += v * wz1[k * 2 + 1];
        ct0 += v * wt1[k * 2 + 0];
        ct1 += v * wt1[k * 2 + 1];
    }
    cz0 = fmaxf(cz0, 0.f); cz1 = fmaxf(cz1, 0.f);
    ct0 = fmaxf(ct0, 0.f); ct1 = fmaxf(ct1, 0.f);
    out[b] = cz0 * wz2[0] + cz1 * wz2[1] + bz2[0];
    out[256 + b] = ct0 * wt2[0] + ct1 * wt2[1] + bt2[0];
}

extern "C" void kernel_launch(void* const* d_in, const int* in_sizes, int n_in,
                              void* d_out, int out_size, void* d_ws, size_t ws_size,
                              hipStream_t stream) {
    const int*   inputA = (const int*)d_in[0];
    const float* inputB = (const float*)d_in[1];
    const float* emb = (const float*)d_in[2];
    const float* w1  = (const float*)d_in[3];
    const float* b1  = (const float*)d_in[4];
    const float* w2  = (const float*)d_in[5];
    const float* b2  = (const float*)d_in[6];
    const float* w3  = (const float*)d_in[7];
    const float* b3  = (const float*)d_in[8];
    const float* k1f = (const float*)d_in[9];
    const float* r1f = (const float*)d_in[10];
    const float* bb1f= (const float*)d_in[11];
    const float* k1b = (const float*)d_in[12];
    const float* r1b = (const float*)d_in[13];
    const float* bb1b= (const float*)d_in[14];
    const float* k2f = (const float*)d_in[15];
    const float* r2f = (const float*)d_in[16];
    const float* bb2f= (const float*)d_in[17];
    const float* k2b = (const float*)d_in[18];
    const float* r2b = (const float*)d_in[19];
    const float* bb2b= (const float*)d_in[20];
    const float* wz1 = (const float*)d_in[21];
    const float* bz1 = (const float*)d_in[22];
    const float* wz2 = (const float*)d_in[23];
    const float* bz2 = (const float*)d_in[24];
    const float* wt1 = (const float*)d_in[25];
    const float* bt1 = (const float*)d_in[26];
    const float* wt2 = (const float*)d_in[27];
    const float* bt2 = (const float*)d_in[28];

    char* ws = (char*)d_ws;
    short* WB1  = (short*)(ws);                  // 512 KB
    short* WB2  = (short*)(ws + 524288);         // 320 KB
    float* xe   = (float*)(ws + 851968);         // 64 KB
    float* h2o  = (float*)(ws + 917504);         // 128 KB
    float* c1st = (float*)(ws + 1048576);        // 256 KB
    short* h1st = (short*)(ws + 1310720);        // 128 KB
    float* c2st = (float*)(ws + 1441792);        // 128 KB
    short* h2st = (short*)(ws + 1572864);        // 64 KB
    short* yfr  = (short*)(ws + 2097152);        // 67.1 MB
    short* xg   = (short*)(ws + 69206016);       // TC*512 KB + 64 KB slack (shared xg/yg)
    float* out  = (float*)d_out;

    // pick time-chunk length from available workspace (64 KB slack for prefetch over-read)
    const size_t fixed = 69206016;
    int TC = 32;
    const int cands[5] = {512, 256, 128, 64, 32};
    for (int i = 0; i < 5; i++) {
        if (fixed + (size_t)cands[i] * 524288 + 65536 <= ws_size) { TC = cands[i]; break; }
    }
    const int NC = 512 / TC;

    prep_weights<<<1024, 256, 0, stream>>>(k1f, r1f, k1b, r1b, k2f, r2f, k2b, r2b, WB1, WB2);
    embed_kernel<<<256, 256, 0, stream>>>(inputA, emb, w1, b1, w2, b2, w3, b3, xe);
    for (int c = 0; c < NC; c++) {
        int t0 = c * TC;
        gemm1_kernel<<<dim3(16, TC / 8, 2), 512, 0, stream>>>(inputB, WB1, bb1f, bb1b, xg, t0, TC);
        lstm1_kernel<<<32, 512, 0, stream>>>(xg, WB1, yfr, c1st, h1st, t0, TC, c == 0);
    }
    for (int c = 0; c < NC; c++) {
        int t0 = c * TC;
        gemm2_kernel<<<dim3(16, TC / 8, 2), 256, 0, stream>>>(yfr, WB2, bb2f, bb2b, xg, t0, TC);
        lstm2_kernel<<<32, 256, 0, stream>>>(xg, WB2, c2st, h2st, h2o, t0, TC, c == 0, c == NC - 1);
    }
    heads_kernel<<<1, 256, 0, stream>>>(xe, h2o, wz1, bz1, wz2, bz2, wt1, bt1, wt2, bt2, out);
}

// Round 6
// 834.734 us; speedup vs baseline: 1.2832x; 1.0893x over previous
//
#include <hip/hip_runtime.h>

typedef __attribute__((ext_vector_type(8))) short s8v;
typedef __attribute__((ext_vector_type(4))) short s4v;
typedef __attribute__((ext_vector_type(4))) float f4v;

#if __has_builtin(__builtin_amdgcn_exp2f)
#define EXP2(x) __builtin_amdgcn_exp2f(x)
#else
#define EXP2(x) exp2f(x)
#endif
#if __has_builtin(__builtin_amdgcn_rcpf)
#define RCP(x) __builtin_amdgcn_rcpf(x)
#else
#define RCP(x) (1.0f/(x))
#endif

#define LOG2E 1.4426950408889634f

__device__ __forceinline__ short f2bf(float f) {
    union { float f; unsigned u; } x; x.f = f;
    unsigned r = (x.u + 0x7FFFu + ((x.u >> 16) & 1u)) >> 16;
    return (short)r;
}
__device__ __forceinline__ float bf2f(short s) {
    union { unsigned u; float f; } x; x.u = ((unsigned)(unsigned short)s) << 16;
    return x.f;
}
// LDS-visibility barrier WITHOUT vmcnt drain (keeps prefetch/stores in flight).
__device__ __forceinline__ void lds_barrier() {
    asm volatile("s_waitcnt lgkmcnt(0)\n\ts_barrier" ::: "memory");
}

// ---------------- prep (weights->bf16 B-frag, sigmoid pre-scale) + embed MLP, fused ----------------
__global__ __launch_bounds__(256) void prep_embed_kernel(
        const float* __restrict__ k1f, const float* __restrict__ r1f,
        const float* __restrict__ k1b, const float* __restrict__ r1b,
        const float* __restrict__ k2f, const float* __restrict__ r2f,
        const float* __restrict__ k2b, const float* __restrict__ r2b,
        short* __restrict__ WB1, short* __restrict__ WB2,
        const int* __restrict__ inputA, const float* __restrict__ emb,
        const float* __restrict__ w1, const float* __restrict__ b1,
        const float* __restrict__ w2, const float* __restrict__ b2,
        const float* __restrict__ w3, const float* __restrict__ b3,
        float* __restrict__ xe) {
    if (blockIdx.x < 1024) {
        int idx = blockIdx.x * 256 + threadIdx.x;
        if (idx < 262144) {  // 2*32*8*64*8
            int j = idx & 7, l = (idx >> 3) & 63, c = (idx >> 9) & 7, n = (idx >> 12) & 31, d = (idx >> 17) & 1;
            int coln = n * 16 + (l & 15);
            int k = c * 32 + ((l >> 4) * 8) + j;
            const float* Wk = d ? k1b : k1f;
            const float* Wr = d ? r1b : r1f;
            float v = (c < 4) ? Wk[k * 512 + coln] : Wr[(k - 128) * 512 + coln];
            float sc = ((n >> 3) == 2) ? 1.0f : -LOG2E;  // gate: 0=i,1=f,2=cc,3=o
            WB1[idx] = f2bf(v * sc);
        }
        if (idx < 163840) {  // 2*16*10*64*8
            int d = idx / 81920, r0 = idx % 81920;
            int n = r0 / 5120, r1 = r0 % 5120;
            int c = r1 / 512, li = r1 % 512;
            int l = li >> 3, j = li & 7;
            int coln = n * 16 + (l & 15);
            int k = c * 32 + ((l >> 4) * 8) + j;
            const float* Wk = d ? k2b : k2f;
            const float* Wr = d ? r2b : r2f;
            float v = (k < 256) ? Wk[k * 256 + coln] : Wr[(k - 256) * 256 + coln];
            float sc = ((n >> 2) == 2) ? 1.0f : -LOG2E;
            WB2[idx] = f2bf(v * sc);
        }
        return;
    }
    // embed role (exact fp32)
    __shared__ float row[600];
    __shared__ float h1[256];
    __shared__ float h2[128];
    int b = blockIdx.x - 1024, t = threadIdx.x;
    if (t < 200) {
        int idx = inputA[b * 200 + t];
        row[t * 3 + 0] = emb[idx * 3 + 0];
        row[t * 3 + 1] = emb[idx * 3 + 1];
        row[t * 3 + 2] = emb[idx * 3 + 2];
    }
    __syncthreads();
    float a = b1[t];
    for (int k = 0; k < 600; k++) a += row[k] * w1[k * 256 + t];
    h1[t] = fmaxf(a, 0.f);
    __syncthreads();
    if (t < 128) {
        float a2 = b2[t];
        for (int k = 0; k < 256; k++) a2 += h1[k] * w2[k * 128 + t];
        h2[t] = fmaxf(a2, 0.f);
    }
    __syncthreads();
    if (t < 64) {
        float a3 = b3[t];
        for (int k = 0; k < 128; k++) a3 += h2[k] * w3[k * 64 + t];
        xe[b * 64 + t] = fmaxf(a3, 0.f);
    }
}

// ---------------- phase A: lstm1 recurrence (blocks 0..31, chunk cl) ----------------
// ----------------          + gemm1 xg precompute (blocks 32.., chunk cg) ----------------
// Launched with dynamic LDS pad so total LDS/block > 80KB -> no two blocks share a CU:
// the 32 recurrence blocks (dispatched first) each own their CU.
__global__ __launch_bounds__(512, 2) void phaseA(
        const float* __restrict__ x, const short* __restrict__ WB1,
        const float* __restrict__ bbf, const float* __restrict__ bbb,
        const short* __restrict__ xg_r, short* __restrict__ xg_w,
        short* __restrict__ yfr, float* __restrict__ c1st, short* __restrict__ h1st,
        int cl, int cg, int TC, int NC) {
    __shared__ short hA[2048];
    __shared__ short hB[2048];
    __shared__ short axf[16384];  // gemm staging: [sl][c][slot(64)][8], swizzled
    const int tid = threadIdx.x, lane = tid & 63, w = tid >> 6;

    if (blockIdx.x >= 32) {
        // ================= GEMM1 role: xg(chunk cg) = x @ Wk + b =================
        if (cg >= NC) return;
        const int t0 = cg * TC;
        const int g = blockIdx.x - 32;
        const int tgn = TC >> 3;
        const int btile = g & 15;
        const int rest = g >> 4;
        const int tg = rest % tgn;
        const int dir = rest / tgn;
        const int b0 = btile << 4;
        {   // stage A frags for slice sl = w (coalesced 512B segments + XOR swizzle)
            int tglob = t0 + tg * 8 + w;
            if (dir) tglob = 511 - tglob;
            const int half = lane >> 5;
            const int f0 = (lane & 31) * 4;
            const int c = f0 >> 5, qq = (f0 >> 3) & 3, j0 = f0 & 7;
#pragma unroll
            for (int rr = 0; rr < 8; rr++) {
                const int m = rr * 2 + half;
                const float* xp = x + ((size_t)(b0 + m) * 512 + tglob) * 128 + f0;
                f4v v4 = *(const f4v*)xp;
                const int slot = (qq << 4) | ((m ^ qq ^ (c << 1)) & 15);
                s4v pk;
#pragma unroll
                for (int j = 0; j < 4; j++) pk[j] = f2bf(v4[j]);
                *(s4v*)&axf[(((w * 4 + c) * 64 + slot) * 8) + j0] = pk;
            }
        }
        s8v wf[4][4];
#pragma unroll
        for (int ti = 0; ti < 4; ti++)
#pragma unroll
            for (int c = 0; c < 4; c++)
                wf[ti][c] = *(const s8v*)(WB1 + ((((dir * 32 + (w + 8 * ti)) * 8) + c) * 64 + lane) * 8);
        const float* bb = dir ? bbb : bbf;
        float bias[4];
#pragma unroll
        for (int ti = 0; ti < 4; ti++) {
            const int tile = w + 8 * ti;
            float sc = ((tile >> 3) == 2) ? 1.0f : -LOG2E;
            bias[ti] = sc * bb[tile * 16 + (lane & 15)];
        }
        __syncthreads();
        const size_t sb = dir * 16 + btile;
#pragma unroll 2
        for (int sl = 0; sl < 8; sl++) {
            s8v a[4];
#pragma unroll
            for (int c = 0; c < 4; c++) {
                const int slot = lane ^ (lane >> 4) ^ (c << 1);
                a[c] = *(const s8v*)&axf[((sl * 4 + c) * 64 + slot) * 8];
            }
            f4v acc[4];
#pragma unroll
            for (int ti = 0; ti < 4; ti++) { f4v z = {0.f, 0.f, 0.f, 0.f}; acc[ti] = z; }
#pragma unroll
            for (int c = 0; c < 4; c++)
#pragma unroll
                for (int ti = 0; ti < 4; ti++)
                    acc[ti] = __builtin_amdgcn_mfma_f32_16x16x32_bf16(a[c], wf[ti][c], acc[ti], 0, 0, 0);
            short* outp = xg_w + ((sb * TC + (size_t)(tg * 8 + sl)) * 8 + w) * 1024 + lane * 8;
#pragma unroll
            for (int p = 0; p < 2; p++) {
                s8v v;
#pragma unroll
                for (int j = 0; j < 4; j++) {
                    v[j]     = f2bf(acc[2 * p][j]     + bias[2 * p]);
                    v[4 + j] = f2bf(acc[2 * p + 1][j] + bias[2 * p + 1]);
                }
                *(s8v*)(outp + p * 512) = v;
            }
        }
        return;
    }

    // ================= LSTM1 recurrence role (h@Wr only), 2-step unrolled =================
    if (cl < 0) return;
    const int t0 = cl * TC;
    const int first = (cl == 0);
    const int btile = blockIdx.x & 15, dir = blockIdx.x >> 4;
    const int col = lane & 15, q = lane >> 4, u = (w << 4) + col;
    const int sb = dir * 16 + btile;

    s8v wf[4][4];  // h-part chunks 4..7
#pragma unroll
    for (int ti = 0; ti < 4; ti++)
#pragma unroll
        for (int c = 0; c < 4; c++)
            wf[ti][c] = *(const s8v*)(WB1 + ((((dir * 32 + (w + 8 * ti)) * 8) + 4 + c) * 64 + lane) * 8);

    float cst[4], hl[4];
    if (first) {
#pragma unroll
        for (int r = 0; r < 4; r++) cst[r] = 0.f;
        for (int i = tid; i < 2048; i += 512) hA[i] = 0;
    } else {
        f4v cv = *(const f4v*)(c1st + ((size_t)sb * 8 + w) * 256 + lane * 4);
#pragma unroll
        for (int r = 0; r < 4; r++) cst[r] = cv[r];
        for (int i = tid; i < 2048; i += 512) hA[i] = h1st[sb * 2048 + i];
    }
    __syncthreads();

    const short* xgp = xg_r + (size_t)sb * TC * 8192 + w * 1024 + lane * 8;
    s8v pe0 = *(const s8v*)(xgp);
    s8v pe1 = *(const s8v*)(xgp + 512);
    s8v po0 = *(const s8v*)(xgp + 8192);
    s8v po1 = *(const s8v*)(xgp + 8192 + 512);

    const int hidx = (w >> 1) * 512 + ((u >> 3) & 3) * 128 + (u & 7);

    for (int s = 0; s < TC; s += 2) {
        // ---- even step s: read hA, write hB ----
        {
            s8v ah[4];
#pragma unroll
            for (int c = 0; c < 4; c++) ah[c] = *(const s8v*)&hA[(c * 64 + lane) * 8];
            if (w >= 4 && s > 0) {  // store h(s-1)
                int tp = t0 + s - 1;
                if (dir) tp = 511 - tp;
                s8v hv = (w == 4) ? ah[0] : (w == 5) ? ah[1] : (w == 6) ? ah[2] : ah[3];
                *(s8v*)(yfr + (((size_t)(btile * 512 + tp) * 8) + dir * 4 + (w - 4)) * 512 + lane * 8) = hv;
            }
            f4v acc[4];
#pragma unroll
            for (int r = 0; r < 4; r++) {
                acc[0][r] = bf2f(pe0[r]);
                acc[1][r] = bf2f(pe0[4 + r]);
                acc[2][r] = bf2f(pe1[r]);
                acc[3][r] = bf2f(pe1[4 + r]);
            }
            {   // prefetch for step s+2 (buffer has slack past the end)
                const short* np = xgp + (size_t)(s + 2) * 8192;
                pe0 = *(const s8v*)np;
                pe1 = *(const s8v*)(np + 512);
            }
#pragma unroll
            for (int c = 0; c < 4; c++)
#pragma unroll
                for (int ti = 0; ti < 4; ti++)
                    acc[ti] = __builtin_amdgcn_mfma_f32_16x16x32_bf16(ah[c], wf[ti][c], acc[ti], 0, 0, 0);
#pragma unroll
            for (int r = 0; r < 4; r++) {
                float iv = RCP(1.0f + EXP2(acc[0][r]));
                float fv = RCP(1.0f + EXP2(acc[1][r]));
                float ov = RCP(1.0f + EXP2(acc[3][r]));
                float ccv = fmaxf(acc[2][r], 0.f);
                cst[r] = fv * cst[r] + iv * ccv;
                hl[r] = ov * fmaxf(cst[r], 0.f);
            }
#pragma unroll
            for (int r = 0; r < 4; r++)
                hB[hidx + ((q * 4 + r) << 3)] = f2bf(hl[r]);
            lds_barrier();
        }
        // ---- odd step s+1: read hB, write hA ----
        {
            s8v ah[4];
#pragma unroll
            for (int c = 0; c < 4; c++) ah[c] = *(const s8v*)&hB[(c * 64 + lane) * 8];
            if (w >= 4) {  // store h(s)
                int tp = t0 + s;
                if (dir) tp = 511 - tp;
                s8v hv = (w == 4) ? ah[0] : (w == 5) ? ah[1] : (w == 6) ? ah[2] : ah[3];
                *(s8v*)(yfr + (((size_t)(btile * 512 + tp) * 8) + dir * 4 + (w - 4)) * 512 + lane * 8) = hv;
            }
            f4v acc[4];
#pragma unroll
            for (int r = 0; r < 4; r++) {
                acc[0][r] = bf2f(po0[r]);
                acc[1][r] = bf2f(po0[4 + r]);
                acc[2][r] = bf2f(po1[r]);
                acc[3][r] = bf2f(po1[4 + r]);
            }
            {   // prefetch for step s+3
                const short* np = xgp + (size_t)(s + 3) * 8192;
                po0 = *(const s8v*)np;
                po1 = *(const s8v*)(np + 512);
            }
#pragma unroll
            for (int c = 0; c < 4; c++)
#pragma unroll
                for (int ti = 0; ti < 4; ti++)
                    acc[ti] = __builtin_amdgcn_mfma_f32_16x16x32_bf16(ah[c], wf[ti][c], acc[ti], 0, 0, 0);
#pragma unroll
            for (int r = 0; r < 4; r++) {
                float iv = RCP(1.0f + EXP2(acc[0][r]));
                float fv = RCP(1.0f + EXP2(acc[1][r]));
                float ov = RCP(1.0f + EXP2(acc[3][r]));
                float ccv = fmaxf(acc[2][r], 0.f);
                cst[r] = fv * cst[r] + iv * ccv;
                hl[r] = ov * fmaxf(cst[r], 0.f);
            }
#pragma unroll
            for (int r = 0; r < 4; r++)
                hA[hidx + ((q * 4 + r) << 3)] = f2bf(hl[r]);
            lds_barrier();
        }
    }
    // final h(TC-1) is in hA
    if (w >= 4) {
        int tp = t0 + TC - 1;
        if (dir) tp = 511 - tp;
        s8v hv = *(const s8v*)&hA[((w - 4) * 64 + lane) * 8];
        *(s8v*)(yfr + (((size_t)(btile * 512 + tp) * 8) + dir * 4 + (w - 4)) * 512 + lane * 8) = hv;
    }
    f4v cv;
#pragma unroll
    for (int r = 0; r < 4; r++) cv[r] = cst[r];
    *(f4v*)(c1st + ((size_t)sb * 8 + w) * 256 + lane * 4) = cv;
    for (int i = tid; i < 2048; i += 512) h1st[sb * 2048 + i] = hA[i];
}

// ---------------- phase B: lstm2 recurrence (blocks 0..31) + gemm2 (blocks 32..) ----------------
__global__ __launch_bounds__(256, 2) void phaseB(
        const short* __restrict__ yfr, const short* __restrict__ WB2,
        const float* __restrict__ bbf, const float* __restrict__ bbb,
        const short* __restrict__ yg_r, short* __restrict__ yg_w,
        float* __restrict__ c2st, short* __restrict__ h2st, float* __restrict__ h2o,
        int cl, int cg, int TC, int NC) {
    __shared__ short hA[1024];
    __shared__ short hB[1024];
    const int tid = threadIdx.x, lane = tid & 63, w = tid >> 6;

    if (blockIdx.x >= 32) {
        // ================= GEMM2 role: yg(chunk cg) = y @ Wk2 + b =================
        if (cg >= NC) return;
        const int t0 = cg * TC;
        const int g = blockIdx.x - 32;
        const int tgn = TC >> 3;
        const int btile = g & 15;
        const int rest = g >> 4;
        const int tg = rest % tgn;
        const int dir = rest / tgn;
        s8v wf[4][8];
#pragma unroll
        for (int ti = 0; ti < 4; ti++)
#pragma unroll
            for (int c = 0; c < 8; c++)
                wf[ti][c] = *(const s8v*)(WB2 + ((((dir * 16 + (w + 4 * ti)) * 10) + c) * 64 + lane) * 8);
        const float* bb = dir ? bbb : bbf;
        float bias[4];
#pragma unroll
        for (int ti = 0; ti < 4; ti++) {
            const int tile = w + 4 * ti;
            float sc = ((tile >> 2) == 2) ? 1.0f : -LOG2E;
            bias[ti] = sc * bb[tile * 16 + (lane & 15)];
        }
        const size_t sb = dir * 16 + btile;
#pragma unroll 2
        for (int sl = 0; sl < 8; sl++) {
            int tglob = t0 + tg * 8 + sl;
            if (dir) tglob = 511 - tglob;
            s8v a[8];
#pragma unroll
            for (int c = 0; c < 8; c++)
                a[c] = *(const s8v*)(yfr + (((size_t)(btile * 512 + tglob) * 8) + c) * 512 + lane * 8);
            f4v acc[4];
#pragma unroll
            for (int ti = 0; ti < 4; ti++) { f4v z = {0.f, 0.f, 0.f, 0.f}; acc[ti] = z; }
#pragma unroll
            for (int c = 0; c < 8; c++)
#pragma unroll
                for (int ti = 0; ti < 4; ti++)
                    acc[ti] = __builtin_amdgcn_mfma_f32_16x16x32_bf16(a[c], wf[ti][c], acc[ti], 0, 0, 0);
            short* outp = yg_w + ((sb * TC + (size_t)(tg * 8 + sl)) * 4 + w) * 1024 + lane * 8;
#pragma unroll
            for (int p = 0; p < 2; p++) {
                s8v v;
#pragma unroll
                for (int j = 0; j < 4; j++) {
                    v[j]     = f2bf(acc[2 * p][j]     + bias[2 * p]);
                    v[4 + j] = f2bf(acc[2 * p + 1][j] + bias[2 * p + 1]);
                }
                *(s8v*)(outp + p * 512) = v;
            }
        }
        return;
    }

    // ================= LSTM2 recurrence role =================
    if (cl < 0) return;
    const int first = (cl == 0), last = (cl == NC - 1);
    const int btile = blockIdx.x & 15, dir = blockIdx.x >> 4;
    const int b0 = btile << 4;
    const int col = lane & 15, q = lane >> 4, u = (w << 4) + col;
    const int sb = dir * 16 + btile;

    s8v wf[4][2];  // h-part chunks 8,9
#pragma unroll
    for (int ti = 0; ti < 4; ti++)
#pragma unroll
        for (int c = 0; c < 2; c++)
            wf[ti][c] = *(const s8v*)(WB2 + ((((dir * 16 + (w + 4 * ti)) * 10) + 8 + c) * 64 + lane) * 8);

    float cst[4], hl[4];
    if (first) {
#pragma unroll
        for (int r = 0; r < 4; r++) cst[r] = 0.f;
        for (int i = tid; i < 1024; i += 256) hA[i] = 0;
    } else {
        f4v cv = *(const f4v*)(c2st + ((size_t)sb * 4 + w) * 256 + lane * 4);
#pragma unroll
        for (int r = 0; r < 4; r++) cst[r] = cv[r];
        for (int i = tid; i < 1024; i += 256) hA[i] = h2st[sb * 1024 + i];
    }
    __syncthreads();

    const short* ygp = yg_r + (size_t)sb * TC * 4096 + w * 1024 + lane * 8;
    s8v pe0 = *(const s8v*)(ygp);
    s8v pe1 = *(const s8v*)(ygp + 512);
    s8v po0 = *(const s8v*)(ygp + 4096);
    s8v po1 = *(const s8v*)(ygp + 4096 + 512);

    const int hidx = (w >> 1) * 512 + ((u >> 3) & 3) * 128 + (u & 7);

    for (int s = 0; s < TC; s += 2) {
        // ---- even step: read hA, write hB ----
        {
            s8v ah[2];
#pragma unroll
            for (int c = 0; c < 2; c++) ah[c] = *(const s8v*)&hA[(c * 64 + lane) * 8];
            f4v acc[4];
#pragma unroll
            for (int r = 0; r < 4; r++) {
                acc[0][r] = bf2f(pe0[r]);
                acc[1][r] = bf2f(pe0[4 + r]);
                acc[2][r] = bf2f(pe1[r]);
                acc[3][r] = bf2f(pe1[4 + r]);
            }
            {
                const short* np = ygp + (size_t)(s + 2) * 4096;
                pe0 = *(const s8v*)np;
                pe1 = *(const s8v*)(np + 512);
            }
#pragma unroll
            for (int c = 0; c < 2; c++)
#pragma unroll
                for (int ti = 0; ti < 4; ti++)
                    acc[ti] = __builtin_amdgcn_mfma_f32_16x16x32_bf16(ah[c], wf[ti][c], acc[ti], 0, 0, 0);
#pragma unroll
            for (int r = 0; r < 4; r++) {
                float iv = RCP(1.0f + EXP2(acc[0][r]));
                float fv = RCP(1.0f + EXP2(acc[1][r]));
                float ov = RCP(1.0f + EXP2(acc[3][r]));
                float ccv = fmaxf(acc[2][r], 0.f);
                cst[r] = fv * cst[r] + iv * ccv;
                hl[r] = ov * fmaxf(cst[r], 0.f);
            }
#pragma unroll
            for (int r = 0; r < 4; r++)
                hB[hidx + ((q * 4 + r) << 3)] = f2bf(hl[r]);
            lds_barrier();
        }
        // ---- odd step: read hB, write hA ----
        {
            s8v ah[2];
#pragma unroll
            for (int c = 0; c < 2; c++) ah[c] = *(const s8v*)&hB[(c * 64 + lane) * 8];
            f4v acc[4];
#pragma unroll
            for (int r = 0; r < 4; r++) {
                acc[0][r] = bf2f(po0[r]);
                acc[1][r] = bf2f(po0[4 + r]);
                acc[2][r] = bf2f(po1[r]);
                acc[3][r] = bf2f(po1[4 + r]);
            }
            {
                const short* np = ygp + (size_t)(s + 3) * 4096;
                po0 = *(const s8v*)np;
                po1 = *(const s8v*)(np + 512);
            }
#pragma unroll
            for (int c = 0; c < 2; c++)
#pragma unroll
                for (int ti = 0; ti < 4; ti++)
                    acc[ti] = __builtin_amdgcn_mfma_f32_16x16x32_bf16(ah[c], wf[ti][c], acc[ti], 0, 0, 0);
#pragma unroll
            for (int r = 0; r < 4; r++) {
                float iv = RCP(1.0f + EXP2(acc[0][r]));
                float fv = RCP(1.0f + EXP2(acc[1][r]));
                float ov = RCP(1.0f + EXP2(acc[3][r]));
                float ccv = fmaxf(acc[2][r], 0.f);
                cst[r] = fv * cst[r] + iv * ccv;
                hl[r] = ov * fmaxf(cst[r], 0.f);
            }
#pragma unroll
            for (int r = 0; r < 4; r++)
                hA[hidx + ((q * 4 + r) << 3)] = f2bf(hl[r]);
            lds_barrier();
        }
    }
    f4v cv;
#pragma unroll
    for (int r = 0; r < 4; r++) cv[r] = cst[r];
    *(f4v*)(c2st + ((size_t)sb * 4 + w) * 256 + lane * 4) = cv;
    for (int i = tid; i < 1024; i += 256) h2st[sb * 1024 + i] = hA[i];
    if (last) {
#pragma unroll
        for (int r = 0; r < 4; r++)
            h2o[((dir * 256) + b0 + q * 4 + r) * 64 + u] = hl[r];
    }
}

// ---------------- final heads (fp32) ----------------
__global__ void heads_kernel(const float* __restrict__ xe, const float* __restrict__ h2o,
                             const float* __restrict__ wz1, const float* __restrict__ bz1,
                             const float* __restrict__ wz2, const float* __restrict__ bz2,
                             const float* __restrict__ wt1, const float* __restrict__ bt1,
                             const float* __restrict__ wt2, const float* __restrict__ bt2,
                             float* __restrict__ out) {
    int b = threadIdx.x;  // 256 threads, 1 block
    float cz0 = bz1[0], cz1 = bz1[1], ct0 = bt1[0], ct1 = bt1[1];
    for (int k = 0; k < 192; k++) {
        float v = (k < 64) ? xe[b * 64 + k]
                : (k < 128) ? h2o[b * 64 + (k - 64)]
                            : h2o[(256 + b) * 64 + (k - 128)];
        cz0 += v * wz1[k * 2 + 0];
        cz1 += v * wz1[k * 2 + 1];
        ct0 += v * wt1[k * 2 + 0];
        ct1 += v * wt1[k * 2 + 1];
    }
    cz0 = fmaxf(cz0, 0.f); cz1 = fmaxf(cz1, 0.f);
    ct0 = fmaxf(ct0, 0.f); ct1 = fmaxf(ct1, 0.f);
    out[b] = cz0 * wz2[0] + cz1 * wz2[1] + bz2[0];
    out[256 + b] = ct0 * wt2[0] + ct1 * wt2[1] + bt2[0];
}

extern "C" void kernel_launch(void* const* d_in, const int* in_sizes, int n_in,
                              void* d_out, int out_size, void* d_ws, size_t ws_size,
                              hipStream_t stream) {
    const int*   inputA = (const int*)d_in[0];
    const float* inputB = (const float*)d_in[1];
    const float* emb = (const float*)d_in[2];
    const float* w1  = (const float*)d_in[3];
    const float* b1  = (const float*)d_in[4];
    const float* w2  = (const float*)d_in[5];
    const float* b2  = (const float*)d_in[6];
    const float* w3  = (const float*)d_in[7];
    const float* b3  = (const float*)d_in[8];
    const float* k1f = (const float*)d_in[9];
    const float* r1f = (const float*)d_in[10];
    const float* bb1f= (const float*)d_in[11];
    const float* k1b = (const float*)d_in[12];
    const float* r1b = (const float*)d_in[13];
    const float* bb1b= (const float*)d_in[14];
    const float* k2f = (const float*)d_in[15];
    const float* r2f = (const float*)d_in[16];
    const float* bb2f= (const float*)d_in[17];
    const float* k2b = (const float*)d_in[18];
    const float* r2b = (const float*)d_in[19];
    const float* bb2b= (const float*)d_in[20];
    const float* wz1 = (const float*)d_in[21];
    const float* bz1 = (const float*)d_in[22];
    const float* wz2 = (const float*)d_in[23];
    const float* bz2 = (const float*)d_in[24];
    const float* wt1 = (const float*)d_in[25];
    const float* bt1 = (const float*)d_in[26];
    const float* wt2 = (const float*)d_in[27];
    const float* bt2 = (const float*)d_in[28];

    char* ws = (char*)d_ws;
    short* WB1  = (short*)(ws);                  // 512 KB
    short* WB2  = (short*)(ws + 524288);         // 320 KB
    float* xe   = (float*)(ws + 851968);         // 64 KB
    float* h2o  = (float*)(ws + 917504);         // 128 KB
    float* c1st = (float*)(ws + 1048576);        // 256 KB
    short* h1st = (short*)(ws + 1310720);        // 128 KB
    float* c2st = (float*)(ws + 1441792);        // 128 KB
    short* h2st = (short*)(ws + 1572864);        // 64 KB
    short* yfr  = (short*)(ws + 2097152);        // 67.1 MB
    short* bufbase = (short*)(ws + 69206016);    // 2 x TC*512KB double buffer + slack
    float* out  = (float*)d_out;

    // TC: double-buffered chunk size from workspace (64 KB slack for prefetch over-read)
    const size_t fixed = 69206016;
    int TC = 32;
    const int cands[3] = {128, 64, 32};
    for (int i = 0; i < 3; i++) {
        if (fixed + 2 * (size_t)cands[i] * 524288 + 65536 <= ws_size) { TC = cands[i]; break; }
    }
    const int NC = 512 / TC;
    const int ggrid = 32 + 4 * TC;                    // 32 recurrence + 16*(TC/8)*2 gemm blocks
    const size_t xgStrideS = (size_t)TC * 262144;     // shorts per xg buffer
    const size_t ygStrideS = (size_t)TC * 131072;     // shorts per yg buffer
    short* xgA = bufbase;          short* xgB = bufbase + xgStrideS;
    short* ygA = bufbase;          short* ygB = bufbase + ygStrideS;
    const unsigned dynA = 49152;   // 40KB static + 48KB -> 88KB/block: no CU sharing
    const unsigned dynB = 81920;   // 4KB static + 80KB -> 84KB/block: no CU sharing

    prep_embed_kernel<<<1280, 256, 0, stream>>>(k1f, r1f, k1b, r1b, k2f, r2f, k2b, r2b,
                                                WB1, WB2, inputA, emb, w1, b1, w2, b2, w3, b3, xe);
    // phase 1: pipeline lstm1(c) with gemm1(c+1)
    phaseA<<<ggrid, 512, dynA, stream>>>(inputB, WB1, bb1f, bb1b, xgA, xgA, yfr, c1st, h1st,
                                         -1, 0, TC, NC);
    for (int c = 0; c < NC; c++) {
        short* rd = (c & 1) ? xgB : xgA;
        short* wr = (c & 1) ? xgA : xgB;
        phaseA<<<ggrid, 512, dynA, stream>>>(inputB, WB1, bb1f, bb1b, rd, wr, yfr, c1st, h1st,
                                             c, c + 1, TC, NC);
    }
    // phase 2: pipeline lstm2(c) with gemm2(c+1)
    phaseB<<<ggrid, 256, dynB, stream>>>(yfr, WB2, bb2f, bb2b, ygA, ygA, c2st, h2st, h2o,
                                         -1, 0, TC, NC);
    for (int c = 0; c < NC; c++) {
        short* rd = (c & 1) ? ygB : ygA;
        short* wr = (c & 1) ? ygA : ygB;
        phaseB<<<ggrid, 256, dynB, stream>>>(yfr, WB2, bb2f, bb2b, rd, wr, c2st, h2st, h2o,
                                             c, c + 1, TC, NC);
    }
    heads_kernel<<<1, 256, 0, stream>>>(xe, h2o, wz1, bz1, wz2, bz2, wt1, bt1, wt2, bt2, out);
}